// Round 1
// baseline (286.949 us; speedup 1.0000x reference)
//
#include <hip/hip_runtime.h>
#include <stdint.h>

#define B 64
#define C 64
#define H 96
#define W 96
#define HW (H * W)          // 9216
#define FEAT (C * HW)       // 589824
#define KSEL (FEAT / 2)     // 294912
#define NBINS 4096
#define BPB 16              // histogram blocks per batch

__device__ __forceinline__ uint32_t mono_key(float f) {
    uint32_t u = __float_as_uint(f);
    // monotone map: larger float -> larger uint
    return (u & 0x80000000u) ? ~u : (u | 0x80000000u);
}

// ---- Kernel 1: per-batch 4096-bin histogram of key's top 12 bits ----
// grid = (BPB, B), block = 256
__global__ void hist_kernel(const float* __restrict__ x, uint32_t* __restrict__ hist) {
    __shared__ uint32_t lh[NBINS];
    const int b = blockIdx.y;
    const int t = threadIdx.x;
    for (int i = t; i < NBINS; i += 256) lh[i] = 0;
    __syncthreads();

    const float4* xb = (const float4*)(x + (size_t)b * FEAT);
    const int n4 = FEAT / 4;  // 147456
    for (int i = blockIdx.x * 256 + t; i < n4; i += BPB * 256) {
        float4 v = xb[i];
        atomicAdd(&lh[mono_key(v.x) >> 20], 1u);
        atomicAdd(&lh[mono_key(v.y) >> 20], 1u);
        atomicAdd(&lh[mono_key(v.z) >> 20], 1u);
        atomicAdd(&lh[mono_key(v.w) >> 20], 1u);
    }
    __syncthreads();

    uint32_t* gh = hist + (size_t)b * NBINS;
    for (int i = t; i < NBINS; i += 256) {
        uint32_t c = lh[i];
        if (c) atomicAdd(&gh[i], c);
    }
}

// ---- Kernel 2: per-batch threshold-bin selection ----
// grid = B, block = 256; chunk t covers bins [t*16, t*16+16)
__global__ void scan_kernel(const uint32_t* __restrict__ hist, uint32_t* __restrict__ thresh) {
    const int b = blockIdx.x;
    const int t = threadIdx.x;
    const uint32_t* h = hist + (size_t)b * NBINS;

    __shared__ uint32_t suf[256];
    __shared__ int chunk_sel;
    __shared__ uint32_t above_sel;

    uint32_t s = 0;
    for (int i = 0; i < 16; ++i) s += h[t * 16 + i];
    suf[t] = s;
    __syncthreads();

    // inclusive suffix sums: suf[t] = sum_{j>=t} part[j]
    for (int off = 1; off < 256; off <<= 1) {
        uint32_t add = (t + off < 256) ? suf[t + off] : 0u;
        __syncthreads();
        suf[t] += add;
        __syncthreads();
    }

    uint32_t above = (t < 255) ? suf[t + 1] : 0u;
    if (above < (uint32_t)KSEL && suf[t] >= (uint32_t)KSEL) {
        chunk_sel = t;
        above_sel = above;
    }
    __syncthreads();

    if (t == 0) {
        const int sel = chunk_sel;
        uint32_t cum = above_sel;
        const uint32_t* hh = h + sel * 16;
        int bin = sel * 16;  // fallback
        for (int i = 15; i >= 0; --i) {
            uint32_t hc = hh[i];
            if (cum + hc >= (uint32_t)KSEL) { bin = sel * 16 + i; break; }
            cum += hc;
        }
        thresh[b] = ((uint32_t)bin) << 20;
    }
}

// ---- Kernel 3: mask + write ----
// one thread per (b, h, w); grid = B*HW/256, block = 256
__global__ void out_kernel(const float* __restrict__ x,
                           const uint32_t* __restrict__ thresh,
                           float* __restrict__ out) {
    const int gid = blockIdx.x * blockDim.x + threadIdx.x;  // over B*HW
    const int b = gid / HW;
    const int hw = gid - b * HW;
    const uint32_t tk = thresh[b];

    const float* xb = x + (size_t)b * FEAT + hw;
    float* ob = out + (size_t)b * FEAT + hw;

    float v[C];
#pragma unroll
    for (int c = 0; c < C; ++c) v[c] = xb[(size_t)c * HW];

    int amax = 0;
    float vmax = v[0];
#pragma unroll
    for (int c = 1; c < C; ++c) {
        if (v[c] > vmax) { vmax = v[c]; amax = c; }
    }

#pragma unroll
    for (int c = 0; c < C; ++c) {
        bool keep = (c < 1) | (c == amax) | (mono_key(v[c]) >= tk);
        ob[(size_t)c * HW] = keep ? v[c] : 0.0f;
    }
}

extern "C" void kernel_launch(void* const* d_in, const int* in_sizes, int n_in,
                              void* d_out, int out_size, void* d_ws, size_t ws_size,
                              hipStream_t stream) {
    const float* x = (const float*)d_in[0];
    float* out = (float*)d_out;

    uint32_t* hist = (uint32_t*)d_ws;                 // B*NBINS u32 = 1 MiB
    uint32_t* thresh = hist + (size_t)B * NBINS;      // B u32

    hipMemsetAsync(hist, 0, (size_t)B * NBINS * sizeof(uint32_t), stream);

    dim3 g1(BPB, B);
    hist_kernel<<<g1, 256, 0, stream>>>(x, hist);
    scan_kernel<<<B, 256, 0, stream>>>(hist, thresh);
    out_kernel<<<(B * HW) / 256, 256, 0, stream>>>(x, thresh, out);
}